// Round 8
// baseline (755.718 us; speedup 1.0000x reference)
//
#include <hip/hip_runtime.h>
#include <hip/hip_bf16.h>

#define IN_DIM   128
#define HIDDEN   256
#define OUT_DIM  128
#define N_NODES  100000
#define N_EDGES  500000
#define N_ROWS   (2 * N_EDGES)   // 1,000,000 rows (2 MC x edges)

typedef __bf16 bf16x8  __attribute__((ext_vector_type(8)));
typedef float  f32x16  __attribute__((ext_vector_type(16)));

// ws layout, FRAGMENT-MAJOR (no LDS in main kernel — direct global->VGPR):
//   12 chunks x 16384 B; chunk cc covers 32 output-cols (n = cc*32 + el).
//   Fragment (ks 0..15, hi 0..1, el 0..31) = 16 B holding
//   W^T[n = cc*32 + el][k = ks*16 + hi*8 + j], j = 0..7, at byte
//     cc*16384 + ks*1024 + hi*512 + el*16 + j*2.
//   A wave's 64 lanes (el,hi) at fixed ks read CONSECUTIVE 16 B -> one
//   coalesced 1 KB load; identical stream for every wave => L1-resident.
//   Chunks 0..7 = W1^T, 8..11 = W2^T.
#define W2S_OFF 131072

__global__ void prep_weights(const float* __restrict__ W1,
                             const float* __restrict__ W2,
                             unsigned char* __restrict__ ws) {
  int t = blockIdx.x * 256 + threadIdx.x;
  if (t < HIDDEN * HIDDEN) {           // W1: [k=256][n=256] row-major input
    int n = t & 255, k = t >> 8;
    __bf16 b = (__bf16)W1[k * HIDDEN + n];
    int byte = (n >> 5) * 16384 + (k >> 4) * 1024 + ((k >> 3) & 1) * 512
             + (n & 31) * 16 + (k & 7) * 2;
    *reinterpret_cast<__bf16*>(ws + byte) = b;
  } else {
    int t2 = t - HIDDEN * HIDDEN;
    if (t2 < HIDDEN * OUT_DIM) {       // W2: [k=256][n=128]
      int n = t2 & 127, k = t2 >> 7;
      __bf16 b = (__bf16)W2[k * OUT_DIM + n];
      int byte = W2S_OFF + (n >> 5) * 16384 + (k >> 4) * 1024
               + ((k >> 3) & 1) * 512 + (n & 31) * 16 + (k & 7) * 2;
      *reinterpret_cast<__bf16*>(ws + byte) = b;
    }
  }
}

static __device__ __forceinline__ unsigned pack_bf16(float a, float b) {
  __bf16 x = (__bf16)a, y = (__bf16)b;
  unsigned short ux = __builtin_bit_cast(unsigned short, x);
  unsigned short uy = __builtin_bit_cast(unsigned short, y);
  return (unsigned)ux | ((unsigned)uy << 16);
}

// 128 threads = 2 waves x 32 edges. Swapped L1 mfma(W,x) + v_permlane32_swap
// register transpose (proven R3/R6), standard L2. NO LDS, NO barriers:
// W fragments are loaded straight from the fragment-major ws stream
// (L1/L2-resident, coalesced) — waves are fully independent, pipes overlap.
__global__ __launch_bounds__(128)
void edge_mlp(const int* __restrict__ eidx,
              const float* __restrict__ x,
              const float* __restrict__ b1,
              const float* __restrict__ b2,
              const unsigned char* __restrict__ ws,
              float* __restrict__ out) {
  const int tid  = threadIdx.x;
  const int wv   = tid >> 6;           // wave 0..1
  const int lane = tid & 63;
  const int el   = lane & 31;          // edge within wave tile
  const int hi   = lane >> 5;          // k half

  const long base = (long)blockIdx.x * 64;
  const long gr   = base + wv * 32 + el;
  const int  mc   = (gr >= N_EDGES) ? 1 : 0;
  const int  e    = (int)(gr - (long)mc * N_EDGES);
  const int  sn   = eidx[e];
  const int  dn   = eidx[N_EDGES + e];
  const float* xs = x + ((long)mc * N_NODES + sn) * IN_DIM;
  const float* xd = x + ((long)mc * N_NODES + dn) * IN_DIM;

  // ---- x fragments (B of swapped L1, 32x32x16): lane holds edge=el,
  //      k = s*16 + hi*8 + j (8 consecutive) ----
  bf16x8 a1[16];
#pragma unroll
  for (int s = 0; s < 16; ++s) {
    int k0 = s * 16 + hi * 8;
    const float* p = (s < 8) ? (xs + k0) : (xd + (k0 - IN_DIM));
    float4 f0 = *reinterpret_cast<const float4*>(p);
    float4 f1 = *reinterpret_cast<const float4*>(p + 4);
    bf16x8 a;
    a[0] = (__bf16)f0.x; a[1] = (__bf16)f0.y; a[2] = (__bf16)f0.z; a[3] = (__bf16)f0.w;
    a[4] = (__bf16)f1.x; a[5] = (__bf16)f1.y; a[6] = (__bf16)f1.z; a[7] = (__bf16)f1.w;
    a1[s] = a;
  }

  // per-lane W-fragment base: + chunk*16384 + ks*1024 selects the fragment
  const unsigned char* wfrag = ws + hi * 512 + el * 16;

  bf16x8 a2[16];

  // ---- layer 1 (swapped): per 32-hcol chunk cc, D[hcol][edge] = W1^T x ----
#pragma unroll
  for (int cc = 0; cc < 8; ++cc) {
    const unsigned char* wc = wfrag + cc * 16384;
    f32x16 acc = {};
#pragma unroll
    for (int ks = 0; ks < 16; ++ks) {
      bf16x8 wf = *reinterpret_cast<const bf16x8*>(wc + ks * 1024);
      acc = __builtin_amdgcn_mfma_f32_32x32x16_bf16(wf, a1[ks], acc, 0, 0, 0);
    }
    // C: col=edge=el, row m=(reg&3)+8*(reg>>2)+4*hi; hcol = cc*32 + m
    float4 bv0 = *reinterpret_cast<const float4*>(b1 + cc * 32 + hi * 4);
    float4 bv1 = *reinterpret_cast<const float4*>(b1 + cc * 32 + 8 + hi * 4);
    float4 bv2 = *reinterpret_cast<const float4*>(b1 + cc * 32 + 16 + hi * 4);
    float4 bv3 = *reinterpret_cast<const float4*>(b1 + cc * 32 + 24 + hi * 4);
    unsigned w0 = pack_bf16(fmaxf(acc[0] + bv0.x, 0.f),  fmaxf(acc[1] + bv0.y, 0.f));
    unsigned w1 = pack_bf16(fmaxf(acc[2] + bv0.z, 0.f),  fmaxf(acc[3] + bv0.w, 0.f));
    unsigned w2 = pack_bf16(fmaxf(acc[4] + bv1.x, 0.f),  fmaxf(acc[5] + bv1.y, 0.f));
    unsigned w3 = pack_bf16(fmaxf(acc[6] + bv1.z, 0.f),  fmaxf(acc[7] + bv1.w, 0.f));
    unsigned w4 = pack_bf16(fmaxf(acc[8] + bv2.x, 0.f),  fmaxf(acc[9] + bv2.y, 0.f));
    unsigned w5 = pack_bf16(fmaxf(acc[10] + bv2.z, 0.f), fmaxf(acc[11] + bv2.w, 0.f));
    unsigned w6 = pack_bf16(fmaxf(acc[12] + bv3.x, 0.f), fmaxf(acc[13] + bv3.y, 0.f));
    unsigned w7 = pack_bf16(fmaxf(acc[14] + bv3.z, 0.f), fmaxf(acc[15] + bv3.w, 0.f));
    // half-wave exchange: vdst' = (a.row0, b.row0); vsrc' = (a.row1, b.row1)
    asm("v_permlane32_swap_b32 %0, %1" : "+v"(w0), "+v"(w2));
    asm("v_permlane32_swap_b32 %0, %1" : "+v"(w1), "+v"(w3));
    asm("v_permlane32_swap_b32 %0, %1" : "+v"(w4), "+v"(w6));
    asm("v_permlane32_swap_b32 %0, %1" : "+v"(w5), "+v"(w7));
    uint4 fe; fe.x = w0; fe.y = w1; fe.z = w2; fe.w = w3;
    uint4 fo; fo.x = w4; fo.y = w5; fo.z = w6; fo.w = w7;
    a2[2 * cc]     = __builtin_bit_cast(bf16x8, fe);
    a2[2 * cc + 1] = __builtin_bit_cast(bf16x8, fo);
  }

  // ---- layer 2 (standard): out[edge][ocol] = h @ W2 + b2 ----
#pragma unroll
  for (int oc = 0; oc < 4; ++oc) {
    const unsigned char* wc = wfrag + W2S_OFF + oc * 16384;
    f32x16 acc = {};
#pragma unroll
    for (int kk = 0; kk < 16; ++kk) {
      bf16x8 wf = *reinterpret_cast<const bf16x8*>(wc + kk * 1024);
      acc = __builtin_amdgcn_mfma_f32_32x32x16_bf16(a2[kk], wf, acc, 0, 0, 0);
    }
    float bvo = b2[oc * 32 + el];
    const long r0 = base + wv * 32;
#pragma unroll
    for (int reg = 0; reg < 16; ++reg) {
      int m = (reg & 3) + 8 * (reg >> 2) + 4 * hi;
      out[(r0 + m) * OUT_DIM + oc * 32 + el] = acc[reg] + bvo;
    }
  }
}

extern "C" void kernel_launch(void* const* d_in, const int* in_sizes, int n_in,
                              void* d_out, int out_size, void* d_ws, size_t ws_size,
                              hipStream_t stream) {
  const int*   eidx = (const int*)d_in[0];
  const float* x    = (const float*)d_in[1];
  const float* b1   = (const float*)d_in[3];
  const float* b2   = (const float*)d_in[5];
  float* out = (float*)d_out;
  unsigned char* ws = (unsigned char*)d_ws;

  prep_weights<<<(HIDDEN * HIDDEN + HIDDEN * OUT_DIM) / 256, 256, 0, stream>>>(
      (const float*)d_in[2], (const float*)d_in[4], ws);

  // 64 rows per block, exact grid (no tail)
  edge_mlp<<<N_ROWS / 64, 128, 0, stream>>>(eidx, x, b1, b2, ws, out);
  (void)in_sizes; (void)n_in; (void)out_size; (void)ws_size;
}

// Round 9
// 360.231 us; speedup vs baseline: 2.0979x; 2.0979x over previous
//
#include <hip/hip_runtime.h>
#include <hip/hip_bf16.h>

#define IN_DIM   128
#define HIDDEN   256
#define OUT_DIM  128
#define N_NODES  100000
#define N_EDGES  500000
#define N_ROWS   (2 * N_EDGES)   // 1,000,000 rows (2 MC x edges)

typedef __bf16 bf16x8  __attribute__((ext_vector_type(8)));
typedef float  f32x16  __attribute__((ext_vector_type(16)));

// ws: 12 chunks x 16384 B. Chunk = 32 output-cols (n) x 512 B (K=256 bf16,
// XOR-swizzled by ((n&7)<<4) in 16B granules). Chunks 0..7 = W1^T, 8..11 = W2^T.
#define W1S_OFF 0
#define W2S_OFF 131072

__global__ void prep_weights(const float* __restrict__ W1,
                             const float* __restrict__ W2,
                             unsigned char* __restrict__ ws) {
  int t = blockIdx.x * 256 + threadIdx.x;
  if (t < HIDDEN * HIDDEN) {           // W1: [k=256][n=256] row-major input
    int n = t & 255, k = t >> 8;
    __bf16 b = (__bf16)W1[k * HIDDEN + n];
    int byte = W1S_OFF + n * 512 + ((k * 2) ^ ((n & 7) << 4));
    *reinterpret_cast<__bf16*>(ws + byte) = b;
  } else {
    int t2 = t - HIDDEN * HIDDEN;
    if (t2 < HIDDEN * OUT_DIM) {       // W2: [k=256][n=128]
      int n = t2 & 127, k = t2 >> 7;
      __bf16 b = (__bf16)W2[k * OUT_DIM + n];
      int byte = W2S_OFF + n * 512 + ((k * 2) ^ ((n & 7) << 4));
      *reinterpret_cast<__bf16*>(ws + byte) = b;
    }
  }
}

static __device__ __forceinline__ unsigned pack_bf16(float a, float b) {
  __bf16 x = (__bf16)a, y = (__bf16)b;
  unsigned short ux = __builtin_bit_cast(unsigned short, x);
  unsigned short uy = __builtin_bit_cast(unsigned short, y);
  return (unsigned)ux | ((unsigned)uy << 16);
}

// L1 epilogue: bias+relu+pack+register-transpose (proven R3/R6 formula).
// C: col=edge=el, row m=(reg&3)+8*(reg>>2)+4*hi.
static __device__ __forceinline__ void h_pack(const f32x16 acc,
                                              const float* __restrict__ b1c,
                                              int hi, bf16x8& oe, bf16x8& oo) {
  float4 bv0 = *reinterpret_cast<const float4*>(b1c + hi * 4);
  float4 bv1 = *reinterpret_cast<const float4*>(b1c + 8 + hi * 4);
  float4 bv2 = *reinterpret_cast<const float4*>(b1c + 16 + hi * 4);
  float4 bv3 = *reinterpret_cast<const float4*>(b1c + 24 + hi * 4);
  unsigned w0 = pack_bf16(fmaxf(acc[0] + bv0.x, 0.f),  fmaxf(acc[1] + bv0.y, 0.f));
  unsigned w1 = pack_bf16(fmaxf(acc[2] + bv0.z, 0.f),  fmaxf(acc[3] + bv0.w, 0.f));
  unsigned w2 = pack_bf16(fmaxf(acc[4] + bv1.x, 0.f),  fmaxf(acc[5] + bv1.y, 0.f));
  unsigned w3 = pack_bf16(fmaxf(acc[6] + bv1.z, 0.f),  fmaxf(acc[7] + bv1.w, 0.f));
  unsigned w4 = pack_bf16(fmaxf(acc[8] + bv2.x, 0.f),  fmaxf(acc[9] + bv2.y, 0.f));
  unsigned w5 = pack_bf16(fmaxf(acc[10] + bv2.z, 0.f), fmaxf(acc[11] + bv2.w, 0.f));
  unsigned w6 = pack_bf16(fmaxf(acc[12] + bv3.x, 0.f), fmaxf(acc[13] + bv3.y, 0.f));
  unsigned w7 = pack_bf16(fmaxf(acc[14] + bv3.z, 0.f), fmaxf(acc[15] + bv3.w, 0.f));
  // half-wave exchange: vdst' = (a.row0, b.row0); vsrc' = (a.row1, b.row1)
  asm("v_permlane32_swap_b32 %0, %1" : "+v"(w0), "+v"(w2));
  asm("v_permlane32_swap_b32 %0, %1" : "+v"(w1), "+v"(w3));
  asm("v_permlane32_swap_b32 %0, %1" : "+v"(w4), "+v"(w6));
  asm("v_permlane32_swap_b32 %0, %1" : "+v"(w5), "+v"(w7));
  uint4 fe; fe.x = w0; fe.y = w1; fe.z = w2; fe.w = w3;
  uint4 fo; fo.x = w4; fo.y = w5; fo.z = w6; fo.w = w7;
  oe = __builtin_bit_cast(bf16x8, fe);
  oo = __builtin_bit_cast(bf16x8, fo);
}

// 128 threads = 2 waves x 32 edges. Swapped L1 mfma(W,x) + permlane transpose
// (proven R3/R6). CHUNK-PAIRED: 6 phases of 32 KB (2 chunks), each phase runs
// TWO independent 16-MFMA chains interleaved (accA/accB) — hides dependent-
// MFMA latency within a wave and halves barrier/drain count (R2-R7 plateau:
// measured cycles ~= sum of pipe cycles, zero overlap; per-wave ILP is the
// untried lever). No launch-bounds min-wave cap (R4: forcing spills ~900 MB).
// NOTE: do NOT use 256-thread variants — R5 miscompiled (absmax 1.75).
__global__ __launch_bounds__(128)
void edge_mlp(const int* __restrict__ eidx,
              const float* __restrict__ x,
              const float* __restrict__ b1,
              const float* __restrict__ b2,
              const unsigned char* __restrict__ ws,
              float* __restrict__ out) {
  __shared__ __align__(16) unsigned char wbuf[32768];   // 2 chunks

  const int tid  = threadIdx.x;
  const int wv   = tid >> 6;           // wave 0..1
  const int lane = tid & 63;
  const int el   = lane & 31;          // edge within wave tile
  const int hi   = lane >> 5;          // k half

  const long base = (long)blockIdx.x * 64;
  const long gr   = base + wv * 32 + el;
  const int  mc   = (gr >= N_EDGES) ? 1 : 0;
  const int  e    = (int)(gr - (long)mc * N_EDGES);
  const int  sn   = eidx[e];
  const int  dn   = eidx[N_EDGES + e];
  const float* xs = x + ((long)mc * N_NODES + sn) * IN_DIM;
  const float* xd = x + ((long)mc * N_NODES + dn) * IN_DIM;

  // ---- x fragments (B of swapped L1, 32x32x16): lane holds edge=el,
  //      k = s*16 + hi*8 + j (8 consecutive) ----
  bf16x8 a1[16];
#pragma unroll
  for (int s = 0; s < 16; ++s) {
    int k0 = s * 16 + hi * 8;
    const float* p = (s < 8) ? (xs + k0) : (xd + (k0 - IN_DIM));
    float4 f0 = *reinterpret_cast<const float4*>(p);
    float4 f1 = *reinterpret_cast<const float4*>(p + 4);
    bf16x8 a;
    a[0] = (__bf16)f0.x; a[1] = (__bf16)f0.y; a[2] = (__bf16)f0.z; a[3] = (__bf16)f0.w;
    a[4] = (__bf16)f1.x; a[5] = (__bf16)f1.y; a[6] = (__bf16)f1.z; a[7] = (__bf16)f1.w;
    a1[s] = a;
  }

  // 128 threads copy TWO chunks (32768 B) in 16 sweeps of 2048 B
#define STAGE2(t)                                                              \
  do {                                                                         \
    const unsigned char* g_ = ws + (t) * 16384;                                \
    _Pragma("unroll")                                                          \
    for (int i_ = 0; i_ < 16; ++i_) {                                          \
      __builtin_amdgcn_global_load_lds(                                        \
          (const __attribute__((address_space(1))) unsigned int*)(g_ + i_ * 2048 + tid * 16), \
          (__attribute__((address_space(3))) unsigned int*)(&wbuf[i_ * 2048 + tid * 16]),     \
          16, 0, 0);                                                           \
    }                                                                          \
  } while (0)

  const int rowb = el * 512;
  const int swz  = (el & 7) << 4;

  bf16x8 a2[16];

  // ---- layer 1 (swapped): 4 phases x 2 chunks; D[hcol][edge] = W1^T x ----
#pragma unroll
  for (int p = 0; p < 4; ++p) {
    const int c0 = 2 * p;
    __syncthreads();                    // previous phase's readers done
    STAGE2(c0);
    __syncthreads();                    // stage drained (vmcnt0 + barrier)
    f32x16 aA = {}, aB = {};
#pragma unroll
    for (int ks = 0; ks < 16; ++ks) {
      const int off = rowb + ((ks * 32 + hi * 16) ^ swz);
      bf16x8 wfA = *reinterpret_cast<const bf16x8*>(&wbuf[off]);
      bf16x8 wfB = *reinterpret_cast<const bf16x8*>(&wbuf[16384 + off]);
      aA = __builtin_amdgcn_mfma_f32_32x32x16_bf16(wfA, a1[ks], aA, 0, 0, 0);
      aB = __builtin_amdgcn_mfma_f32_32x32x16_bf16(wfB, a1[ks], aB, 0, 0, 0);
    }
    h_pack(aA, b1 + c0 * 32,      hi, a2[2 * c0],     a2[2 * c0 + 1]);
    h_pack(aB, b1 + c0 * 32 + 32, hi, a2[2 * c0 + 2], a2[2 * c0 + 3]);
  }

  // ---- layer 2 (standard): 2 phases x 2 chunks; out = h @ W2 + b2 ----
#pragma unroll
  for (int q = 0; q < 2; ++q) {
    const int oc0 = 2 * q;
    __syncthreads();
    STAGE2(8 + oc0);
    __syncthreads();
    f32x16 aA = {}, aB = {};
#pragma unroll
    for (int kk = 0; kk < 16; ++kk) {
      const int off = rowb + ((kk * 32 + hi * 16) ^ swz);
      bf16x8 wfA = *reinterpret_cast<const bf16x8*>(&wbuf[off]);
      bf16x8 wfB = *reinterpret_cast<const bf16x8*>(&wbuf[16384 + off]);
      aA = __builtin_amdgcn_mfma_f32_32x32x16_bf16(a2[kk], wfA, aA, 0, 0, 0);
      aB = __builtin_amdgcn_mfma_f32_32x32x16_bf16(a2[kk], wfB, aB, 0, 0, 0);
    }
    const long r0 = base + wv * 32;
    float bvA = b2[oc0 * 32 + el];
    float bvB = b2[oc0 * 32 + 32 + el];
#pragma unroll
    for (int reg = 0; reg < 16; ++reg) {
      int m = (reg & 3) + 8 * (reg >> 2) + 4 * hi;
      out[(r0 + m) * OUT_DIM + oc0 * 32 + el]      = aA[reg] + bvA;
      out[(r0 + m) * OUT_DIM + oc0 * 32 + 32 + el] = aB[reg] + bvB;
    }
  }
#undef STAGE2
}

extern "C" void kernel_launch(void* const* d_in, const int* in_sizes, int n_in,
                              void* d_out, int out_size, void* d_ws, size_t ws_size,
                              hipStream_t stream) {
  const int*   eidx = (const int*)d_in[0];
  const float* x    = (const float*)d_in[1];
  const float* b1   = (const float*)d_in[3];
  const float* b2   = (const float*)d_in[5];
  float* out = (float*)d_out;
  unsigned char* ws = (unsigned char*)d_ws;

  prep_weights<<<(HIDDEN * HIDDEN + HIDDEN * OUT_DIM) / 256, 256, 0, stream>>>(
      (const float*)d_in[2], (const float*)d_in[4], ws);

  // 64 rows per block, exact grid (no tail)
  edge_mlp<<<N_ROWS / 64, 128, 0, stream>>>(eidx, x, b1, b2, ws, out);
  (void)in_sizes; (void)n_in; (void)out_size; (void)ws_size;
}

// Round 10
// 326.418 us; speedup vs baseline: 2.3152x; 1.1036x over previous
//
#include <hip/hip_runtime.h>
#include <hip/hip_bf16.h>

#define IN_DIM   128
#define HIDDEN   256
#define OUT_DIM  128
#define N_NODES  100000
#define N_EDGES  500000
#define N_ROWS   (2 * N_EDGES)   // 1,000,000 rows (2 MC x edges)

typedef __bf16 bf16x8  __attribute__((ext_vector_type(8)));
typedef float  f32x16  __attribute__((ext_vector_type(16)));

// ws layout:
//   [0, 196608)           12 weight chunks x 16384 B (as R9: 32 n-cols x 512 B,
//                         K=256 bf16, XOR-swizzled by ((n&7)<<4) in 16B granules;
//                         chunks 0..7 = W1^T, 8..11 = W2^T)
//   [196608, +51200000)   xbf: x converted to bf16, row-major [2*N_NODES][128]
//                         (256 B rows). Halves the gather fabric traffic —
//                         the R2-R9 ~400us plateau tracks L2-fill bytes
//                         (gather misses the 4MB/XCD L2 on random node ids),
//                         not any CU pipe.
#define W1S_OFF 0
#define W2S_OFF 131072
#define XBF_OFF 196608

__global__ void prep_weights(const float* __restrict__ W1,
                             const float* __restrict__ W2,
                             unsigned char* __restrict__ ws) {
  int t = blockIdx.x * 256 + threadIdx.x;
  if (t < HIDDEN * HIDDEN) {           // W1: [k=256][n=256] row-major input
    int n = t & 255, k = t >> 8;
    __bf16 b = (__bf16)W1[k * HIDDEN + n];
    int byte = W1S_OFF + n * 512 + ((k * 2) ^ ((n & 7) << 4));
    *reinterpret_cast<__bf16*>(ws + byte) = b;
  } else {
    int t2 = t - HIDDEN * HIDDEN;
    if (t2 < HIDDEN * OUT_DIM) {       // W2: [k=256][n=128]
      int n = t2 & 127, k = t2 >> 7;
      __bf16 b = (__bf16)W2[k * OUT_DIM + n];
      int byte = W2S_OFF + n * 512 + ((k * 2) ^ ((n & 7) << 4));
      *reinterpret_cast<__bf16*>(ws + byte) = b;
    }
  }
}

// x fp32 -> bf16 table (25.6M elements, 8 per thread, fully coalesced)
__global__ __launch_bounds__(256)
void prep_x(const float* __restrict__ x, unsigned char* __restrict__ xbf) {
  long i = ((long)blockIdx.x * 256 + threadIdx.x) * 8;
  float4 f0 = *reinterpret_cast<const float4*>(x + i);
  float4 f1 = *reinterpret_cast<const float4*>(x + i + 4);
  bf16x8 a;
  a[0] = (__bf16)f0.x; a[1] = (__bf16)f0.y; a[2] = (__bf16)f0.z; a[3] = (__bf16)f0.w;
  a[4] = (__bf16)f1.x; a[5] = (__bf16)f1.y; a[6] = (__bf16)f1.z; a[7] = (__bf16)f1.w;
  *reinterpret_cast<bf16x8*>(xbf + i * 2) = a;
}

static __device__ __forceinline__ unsigned pack_bf16(float a, float b) {
  __bf16 x = (__bf16)a, y = (__bf16)b;
  unsigned short ux = __builtin_bit_cast(unsigned short, x);
  unsigned short uy = __builtin_bit_cast(unsigned short, y);
  return (unsigned)ux | ((unsigned)uy << 16);
}

// L1 epilogue: bias+relu+pack+register-transpose (proven R3/R6 formula).
// C: col=edge=el, row m=(reg&3)+8*(reg>>2)+4*hi.
static __device__ __forceinline__ void h_pack(const f32x16 acc,
                                              const float* __restrict__ b1c,
                                              int hi, bf16x8& oe, bf16x8& oo) {
  float4 bv0 = *reinterpret_cast<const float4*>(b1c + hi * 4);
  float4 bv1 = *reinterpret_cast<const float4*>(b1c + 8 + hi * 4);
  float4 bv2 = *reinterpret_cast<const float4*>(b1c + 16 + hi * 4);
  float4 bv3 = *reinterpret_cast<const float4*>(b1c + 24 + hi * 4);
  unsigned w0 = pack_bf16(fmaxf(acc[0] + bv0.x, 0.f),  fmaxf(acc[1] + bv0.y, 0.f));
  unsigned w1 = pack_bf16(fmaxf(acc[2] + bv0.z, 0.f),  fmaxf(acc[3] + bv0.w, 0.f));
  unsigned w2 = pack_bf16(fmaxf(acc[4] + bv1.x, 0.f),  fmaxf(acc[5] + bv1.y, 0.f));
  unsigned w3 = pack_bf16(fmaxf(acc[6] + bv1.z, 0.f),  fmaxf(acc[7] + bv1.w, 0.f));
  unsigned w4 = pack_bf16(fmaxf(acc[8] + bv2.x, 0.f),  fmaxf(acc[9] + bv2.y, 0.f));
  unsigned w5 = pack_bf16(fmaxf(acc[10] + bv2.z, 0.f), fmaxf(acc[11] + bv2.w, 0.f));
  unsigned w6 = pack_bf16(fmaxf(acc[12] + bv3.x, 0.f), fmaxf(acc[13] + bv3.y, 0.f));
  unsigned w7 = pack_bf16(fmaxf(acc[14] + bv3.z, 0.f), fmaxf(acc[15] + bv3.w, 0.f));
  // half-wave exchange: vdst' = (a.row0, b.row0); vsrc' = (a.row1, b.row1)
  asm("v_permlane32_swap_b32 %0, %1" : "+v"(w0), "+v"(w2));
  asm("v_permlane32_swap_b32 %0, %1" : "+v"(w1), "+v"(w3));
  asm("v_permlane32_swap_b32 %0, %1" : "+v"(w4), "+v"(w6));
  asm("v_permlane32_swap_b32 %0, %1" : "+v"(w5), "+v"(w7));
  uint4 fe; fe.x = w0; fe.y = w1; fe.z = w2; fe.w = w3;
  uint4 fo; fo.x = w4; fo.y = w5; fo.z = w6; fo.w = w7;
  oe = __builtin_bit_cast(bf16x8, fe);
  oo = __builtin_bit_cast(bf16x8, fo);
}

// 128 threads = 2 waves x 32 edges. Swapped L1 mfma(W,x) + permlane transpose
// (proven R3/R6/R9). Chunk-paired staging (R9). Gather reads the bf16 table:
// the 256 B bf16 row layout IS the fragment layout -> 16 direct 16 B loads,
// zero conversion VALU, half the fabric bytes.
// NOTE: do NOT use 256-thread variants — R5 miscompiled (absmax 1.75).
__global__ __launch_bounds__(128)
void edge_mlp(const int* __restrict__ eidx,
              const unsigned char* __restrict__ xbf,
              const float* __restrict__ b1,
              const float* __restrict__ b2,
              const unsigned char* __restrict__ ws,
              float* __restrict__ out) {
  __shared__ __align__(16) unsigned char wbuf[32768];   // 2 chunks

  const int tid  = threadIdx.x;
  const int wv   = tid >> 6;           // wave 0..1
  const int lane = tid & 63;
  const int el   = lane & 31;          // edge within wave tile
  const int hi   = lane >> 5;          // k half

  const long base = (long)blockIdx.x * 64;
  const long gr   = base + wv * 32 + el;
  const int  mc   = (gr >= N_EDGES) ? 1 : 0;
  const int  e    = (int)(gr - (long)mc * N_EDGES);
  const int  sn   = eidx[e];
  const int  dn   = eidx[N_EDGES + e];
  const unsigned char* xsb = xbf + ((long)mc * N_NODES + sn) * 256;
  const unsigned char* xdb = xbf + ((long)mc * N_NODES + dn) * 256;

  // ---- x fragments (B of swapped L1, 32x32x16): lane holds edge=el,
  //      k = s*16 + hi*8 + j -> bf16 row byte s*32 + hi*16, 16 B direct ----
  bf16x8 a1[16];
#pragma unroll
  for (int s = 0; s < 16; ++s) {
    const unsigned char* p = (s < 8) ? (xsb + s * 32 + hi * 16)
                                     : (xdb + (s - 8) * 32 + hi * 16);
    a1[s] = *reinterpret_cast<const bf16x8*>(p);
  }

  // 128 threads copy TWO chunks (32768 B) in 16 sweeps of 2048 B
#define STAGE2(t)                                                              \
  do {                                                                         \
    const unsigned char* g_ = ws + (t) * 16384;                                \
    _Pragma("unroll")                                                          \
    for (int i_ = 0; i_ < 16; ++i_) {                                          \
      __builtin_amdgcn_global_load_lds(                                        \
          (const __attribute__((address_space(1))) unsigned int*)(g_ + i_ * 2048 + tid * 16), \
          (__attribute__((address_space(3))) unsigned int*)(&wbuf[i_ * 2048 + tid * 16]),     \
          16, 0, 0);                                                           \
    }                                                                          \
  } while (0)

  const int rowb = el * 512;
  const int swz  = (el & 7) << 4;

  bf16x8 a2[16];

  // ---- layer 1 (swapped): 4 phases x 2 chunks; D[hcol][edge] = W1^T x ----
#pragma unroll
  for (int p = 0; p < 4; ++p) {
    const int c0 = 2 * p;
    __syncthreads();                    // previous phase's readers done
    STAGE2(c0);
    __syncthreads();                    // stage drained (vmcnt0 + barrier)
    f32x16 aA = {}, aB = {};
#pragma unroll
    for (int ks = 0; ks < 16; ++ks) {
      const int off = rowb + ((ks * 32 + hi * 16) ^ swz);
      bf16x8 wfA = *reinterpret_cast<const bf16x8*>(&wbuf[off]);
      bf16x8 wfB = *reinterpret_cast<const bf16x8*>(&wbuf[16384 + off]);
      aA = __builtin_amdgcn_mfma_f32_32x32x16_bf16(wfA, a1[ks], aA, 0, 0, 0);
      aB = __builtin_amdgcn_mfma_f32_32x32x16_bf16(wfB, a1[ks], aB, 0, 0, 0);
    }
    h_pack(aA, b1 + c0 * 32,      hi, a2[2 * c0],     a2[2 * c0 + 1]);
    h_pack(aB, b1 + c0 * 32 + 32, hi, a2[2 * c0 + 2], a2[2 * c0 + 3]);
  }

  // ---- layer 2 (standard): 2 phases x 2 chunks; out = h @ W2 + b2 ----
#pragma unroll
  for (int q = 0; q < 2; ++q) {
    const int oc0 = 2 * q;
    __syncthreads();
    STAGE2(8 + oc0);
    __syncthreads();
    f32x16 aA = {}, aB = {};
#pragma unroll
    for (int kk = 0; kk < 16; ++kk) {
      const int off = rowb + ((kk * 32 + hi * 16) ^ swz);
      bf16x8 wfA = *reinterpret_cast<const bf16x8*>(&wbuf[off]);
      bf16x8 wfB = *reinterpret_cast<const bf16x8*>(&wbuf[16384 + off]);
      aA = __builtin_amdgcn_mfma_f32_32x32x16_bf16(a2[kk], wfA, aA, 0, 0, 0);
      aB = __builtin_amdgcn_mfma_f32_32x32x16_bf16(a2[kk], wfB, aB, 0, 0, 0);
    }
    const long r0 = base + wv * 32;
    float bvA = b2[oc0 * 32 + el];
    float bvB = b2[oc0 * 32 + 32 + el];
#pragma unroll
    for (int reg = 0; reg < 16; ++reg) {
      int m = (reg & 3) + 8 * (reg >> 2) + 4 * hi;
      out[(r0 + m) * OUT_DIM + oc0 * 32 + el]      = aA[reg] + bvA;
      out[(r0 + m) * OUT_DIM + oc0 * 32 + 32 + el] = aB[reg] + bvB;
    }
  }
#undef STAGE2
}

extern "C" void kernel_launch(void* const* d_in, const int* in_sizes, int n_in,
                              void* d_out, int out_size, void* d_ws, size_t ws_size,
                              hipStream_t stream) {
  const int*   eidx = (const int*)d_in[0];
  const float* x    = (const float*)d_in[1];
  const float* b1   = (const float*)d_in[3];
  const float* b2   = (const float*)d_in[5];
  float* out = (float*)d_out;
  unsigned char* ws = (unsigned char*)d_ws;

  prep_weights<<<(HIDDEN * HIDDEN + HIDDEN * OUT_DIM) / 256, 256, 0, stream>>>(
      (const float*)d_in[2], (const float*)d_in[4], ws);

  // x -> bf16 table: 25.6M elements, 8/thread -> 12500 blocks exactly
  prep_x<<<12500, 256, 0, stream>>>(x, ws + XBF_OFF);

  // 64 rows per block, exact grid (no tail)
  edge_mlp<<<N_ROWS / 64, 128, 0, stream>>>(eidx, ws + XBF_OFF, b1, b2, ws, out);
  (void)in_sizes; (void)n_in; (void)out_size; (void)ws_size;
}